// Round 7
// baseline (176.307 us; speedup 1.0000x reference)
//
#include <hip/hip_runtime.h>
#include <hip/hip_bf16.h>
#include <stdint.h>

// ---------------------------------------------------------------------------
// NF4 dequant + linear:  out[M,N] = x[M,K] @ W[N,K]^T + bias
// R7: dequant gather moved off the LDS pipe -> v_perm_b32 register tables.
//  - NF4 codebook as 8 u32 byte-tables in (uniform) registers; per 4 elems:
//    ~25 VALU, 0 LDS reads.  (R6 was LDS-pipe bound: 32 ds_read_b32 LUT
//    lookups per thread-step = 186 cyc/wave on the shared CU LDS pipe.)
//  - A-tile double-buffered gload_lds, no vmcnt drain in loop (R6-verified)
//  - widx/absmax reg-prefetch (T14), same-XCD panel-mate dispatch (R5)
// ---------------------------------------------------------------------------

using short8 = __attribute__((ext_vector_type(8))) short;
using f32x4  = __attribute__((ext_vector_type(4))) float;

#define AS1 __attribute__((address_space(1)))
#define AS3 __attribute__((address_space(3)))

__device__ __forceinline__ void gload16(const void* g, void* l) {
  __builtin_amdgcn_global_load_lds((const AS1 uint32_t*)g, (AS3 uint32_t*)l, 16, 0, 0);
}

__constant__ float NF4_CONST[16] = {
  -1.0f, -0.6961928009986877f, -0.5250730514526367f, -0.39491748809814453f,
  -0.28444138169288635f, -0.18477343022823334f, -0.09105003625154495f, 0.0f,
  0.07958029955625534f, 0.16093020141124725f, 0.24611230194568634f,
  0.33791524171829224f, 0.44070982933044434f, 0.5626170039176941f,
  0.7229568362236023f, 1.0f};

__device__ __forceinline__ ushort f2bf(float f) {
  union { float f; uint32_t u; } v; v.f = f;
  uint32_t r = (v.u + 0x7FFFu + ((v.u >> 16) & 1u)) >> 16;
  return (ushort)r;
}

// ---- Pass A: x f32 -> bf16 ------------------------------------------------
__global__ __launch_bounds__(256) void f32_to_bf16(
    const float* __restrict__ in, ushort* __restrict__ out) {
  const int t = blockIdx.x * 256 + threadIdx.x;
  const int base = t * 8;
  const float4 a = *(const float4*)(in + base);
  const float4 b = *(const float4*)(in + base + 4);
  uint4 o;
  o.x = (uint32_t)f2bf(a.x) | ((uint32_t)f2bf(a.y) << 16);
  o.y = (uint32_t)f2bf(a.z) | ((uint32_t)f2bf(a.w) << 16);
  o.z = (uint32_t)f2bf(b.x) | ((uint32_t)f2bf(b.y) << 16);
  o.w = (uint32_t)f2bf(b.z) | ((uint32_t)f2bf(b.w) << 16);
  *(uint4*)(out + base) = o;
}

// ---- Pass B: fused dequant + 128x128 bf16 GEMM ----------------------------
// LDS: A buf0 16K | A buf1 16K | B 16K = 49152 B.
// Swizzle (R1-verified): 16B slot s of row r holds logical slot s^(r&7).
#define BM 128
#define BN 128
#define BKK 64

// Dequant 4 elems (one int4 of indices) via v_perm register-table gather.
// Tables: tL0..tL3 = low bytes of bf16 codes (entries 0-3,4-7,8-11,12-15),
// tH0..tH3 = high bytes.  perm(a,b,sel): sel byte 0-3 -> b, 4-7 -> a.
#define DQ4(o01, o23, v4, s) do {                                         \
  const uint32_t _i4 = (uint32_t)(v4).x | ((uint32_t)(v4).y << 8) |       \
                 ((uint32_t)(v4).z << 16) | ((uint32_t)(v4).w << 24);     \
  const uint32_t _sel = _i4 & 0x07070707u;                                \
  const uint32_t _ms  = 0x03020100u + ((_i4 & 0x08080808u) >> 1);         \
  const uint32_t _l0 = __builtin_amdgcn_perm(tL1, tL0, _sel);             \
  const uint32_t _l1 = __builtin_amdgcn_perm(tL3, tL2, _sel);             \
  const uint32_t _lo = __builtin_amdgcn_perm(_l1, _l0, _ms);              \
  const uint32_t _h0 = __builtin_amdgcn_perm(tH1, tH0, _sel);             \
  const uint32_t _h1 = __builtin_amdgcn_perm(tH3, tH2, _sel);             \
  const uint32_t _hi = __builtin_amdgcn_perm(_h1, _h0, _ms);              \
  const uint32_t _p01 = __builtin_amdgcn_perm(_hi, _lo, 0x05010400u);     \
  const uint32_t _p23 = __builtin_amdgcn_perm(_hi, _lo, 0x07030602u);     \
  const float _g0 = __builtin_bit_cast(float, _p01 << 16) * (s);          \
  const float _g1 = __builtin_bit_cast(float, _p01 & 0xffff0000u) * (s);  \
  o01 = __builtin_amdgcn_perm(__builtin_bit_cast(uint32_t, _g1),          \
                              __builtin_bit_cast(uint32_t, _g0),          \
                              0x07060302u);                               \
  const float _g2 = __builtin_bit_cast(float, _p23 << 16) * (s);          \
  const float _g3 = __builtin_bit_cast(float, _p23 & 0xffff0000u) * (s);  \
  o23 = __builtin_amdgcn_perm(__builtin_bit_cast(uint32_t, _g3),          \
                              __builtin_bit_cast(uint32_t, _g2),          \
                              0x07060302u);                               \
} while (0)

__global__ __launch_bounds__(256, 3) void gemm_fused(
    const ushort* __restrict__ A, const int* __restrict__ widx,
    const float* __restrict__ absmax, const float* __restrict__ bias,
    float* __restrict__ C, const int M, const int N, const int K,
    const int MP, const int NB) {
  __shared__ char lds[49152];
  const int tid  = threadIdx.x;
  const int wid  = tid >> 6;
  const int lane = tid & 63;

  // R5 dispatch map: id = r + 8*(m + MP*q), n = 8q + r  -> panel-mates on
  // one XCD (id%8 fixed) and co-resident (one window).
  const int r8 = blockIdx.x & 7;
  const int w  = blockIdx.x >> 3;
  const int mP = w % MP;
  const int q  = w / MP;
  const int nP = (q << 3) + r8;
  if (nP >= NB) return;                 // whole-block early exit (padded grid)
  const int row0 = mP * BM;
  const int col0 = nP * BN;
  const int wr = wid >> 1, wc = wid & 1;
  const int KB = K >> 6;

  // register byte-tables of the bf16 NF4 codebook (uniform; loop-invariant)
  uint32_t tL0, tL1, tL2, tL3, tH0, tH1, tH2, tH3;
  {
    uint32_t lo[4], hi[4];
#pragma unroll
    for (int g = 0; g < 4; ++g) {
      uint32_t l = 0, h = 0;
#pragma unroll
      for (int e = 0; e < 4; ++e) {
        const ushort b = f2bf(NF4_CONST[g * 4 + e]);
        l |= (uint32_t)(b & 0xff) << (8 * e);
        h |= (uint32_t)(b >> 8) << (8 * e);
      }
      lo[g] = l; hi[g] = h;
    }
    tL0 = lo[0]; tL1 = lo[1]; tL2 = lo[2]; tL3 = lo[3];
    tH0 = hi[0]; tH1 = hi[1]; tH2 = hi[2]; tH3 = hi[3];
  }

  // per-thread staging constants (pre-swizzled source, rule #21)
  const ushort* gsrcA[4];
  const int*    wsrc[4];
  const float*  asrc[4];
  int bdst[4];
#pragma unroll
  for (int i = 0; i < 4; ++i) {
    const int u = tid + i * 256;
    const int rr = u >> 3;
    const int sl = (u & 7) ^ (rr & 7);
    gsrcA[i] = A + (size_t)(row0 + rr) * K + sl * 8;
    wsrc[i]  = widx + (size_t)(col0 + rr) * K + sl * 8;
    asrc[i]  = absmax + (size_t)(col0 + rr) * KB;
    bdst[i]  = 32768 + i * 4096 + tid * 16;
  }

  // LDS read byte-offsets (match the write swizzle); A offsets relative to
  // the active A buffer, B offsets absolute.
  int offA[2][4], offB[2][4];
#pragma unroll
  for (int ks = 0; ks < 2; ++ks) {
#pragma unroll
    for (int m = 0; m < 4; ++m) {
      const int ra = wr * 64 + m * 16 + (lane & 15);
      offA[ks][m] = ra * 128 + (((ks * 4 + (lane >> 4)) ^ (ra & 7)) * 16);
      const int rb = wc * 64 + m * 16 + (lane & 15);
      offB[ks][m] = 32768 + rb * 128 + (((ks * 4 + (lane >> 4)) ^ (rb & 7)) * 16);
    }
  }

  f32x4 acc[4][4] = {};

  // ---- prologue: stage A(0) into buf0, prefetch q(0)/sc(0) ----
#pragma unroll
  for (int i = 0; i < 4; ++i)
    gload16(gsrcA[i], lds + i * 4096 + wid * 1024);
  int4 q0[4], q1[4]; float sc[4];
#pragma unroll
  for (int i = 0; i < 4; ++i) {
    q0[i] = *(const int4*)(wsrc[i]);
    q1[i] = *(const int4*)(wsrc[i] + 4);
    sc[i] = asrc[i][0];
  }
  __syncthreads();   // one-time full drain; A(0) visible
  int cur = 0;

  for (int kt = 0; kt < K; kt += BKK) {
    // stage A(next) into the other buffer (1 iteration ahead)
    const int ka = (kt + BKK < K) ? kt + BKK : kt;   // clamp keeps count fixed
#pragma unroll
    for (int i = 0; i < 4; ++i)
      gload16(gsrcA[i] + ka, lds + ((cur ^ 1) << 14) + i * 4096 + wid * 1024);
    __builtin_amdgcn_sched_barrier(0);   // pin: A-gloads oldest this iter

    // B stage: v_perm dequant of q(kt) -> swizzled LDS.  (Compiler's vmcnt
    // wait for q here also retires the older A(kt) gloads -> barrier1 needs
    // no vmcnt.)
#pragma unroll
    for (int i = 0; i < 4; ++i) {
      uint4 v;
      DQ4(v.x, v.y, q0[i], sc[i]);
      DQ4(v.z, v.w, q1[i], sc[i]);
      *(uint4*)(lds + bdst[i]) = v;
    }
    // T14: prefetch next widx/absmax (stays in flight across both barriers)
#pragma unroll
    for (int i = 0; i < 4; ++i) {
      q0[i] = *(const int4*)(wsrc[i] + ka);
      q1[i] = *(const int4*)(wsrc[i] + ka + 4);
      sc[i] = asrc[i][ka >> 6];
    }
    __builtin_amdgcn_sched_barrier(0);

    // barrier 1: B ds_writes visible; A(kt) already landed (see above).
    asm volatile("s_waitcnt lgkmcnt(0)" ::: "memory");
    __builtin_amdgcn_s_barrier();
    __builtin_amdgcn_sched_barrier(0);

    const int abase = cur << 14;
#pragma unroll
    for (int ks = 0; ks < 2; ++ks) {
      short8 af[4], bv[4];
#pragma unroll
      for (int m = 0; m < 4; ++m)
        af[m] = *(const short8*)(lds + abase + offA[ks][m]);
#pragma unroll
      for (int n = 0; n < 4; ++n)
        bv[n] = *(const short8*)(lds + offB[ks][n]);
#pragma unroll
      for (int m = 0; m < 4; ++m)
#pragma unroll
        for (int n = 0; n < 4; ++n)
          acc[m][n] = __builtin_amdgcn_mfma_f32_16x16x32_bf16(
              af[m], bv[n], acc[m][n], 0, 0, 0);
    }
    __builtin_amdgcn_sched_barrier(0);

    // barrier 2: raw — ds_reads all consumed by MFMAs already; no vmcnt drain
    __builtin_amdgcn_s_barrier();
    cur ^= 1;
  }

  // epilogue: C/D layout col=lane&15, row=(lane>>4)*4+j (m89-verified)
#pragma unroll
  for (int n = 0; n < 4; ++n) {
    const int gc = col0 + wc * 64 + n * 16 + (lane & 15);
    const float bvadd = bias[gc];
#pragma unroll
    for (int m = 0; m < 4; ++m) {
      const int gr0 = row0 + wr * 64 + m * 16 + ((lane >> 4) * 4);
#pragma unroll
      for (int j = 0; j < 4; ++j)
        C[(size_t)(gr0 + j) * N + gc] = acc[m][n][j] + bvadd;
    }
  }
}

// ---- last-resort fallback (non-conforming shapes): correct but slow -------
__global__ __launch_bounds__(256) void fallback_kernel(
    const float* __restrict__ x, const int* __restrict__ widx,
    const float* __restrict__ absmax, const float* __restrict__ bias,
    float* __restrict__ out, const int M, const int N, const int K) {
  __shared__ float w[4096];
  const int o = blockIdx.x;
  for (int k = threadIdx.x; k < K; k += 256) {
    const long long fi = (long long)o * K + k;
    w[k] = NF4_CONST[widx[fi]] * absmax[fi >> 6];
  }
  __syncthreads();
  for (int m = threadIdx.x; m < M; m += 256) {
    float acc = bias[o];
    const float* xr = x + (size_t)m * K;
    for (int k = 0; k < K; ++k) acc += xr[k] * w[k];
    out[(size_t)m * N + o] = acc;
  }
}

extern "C" void kernel_launch(void* const* d_in, const int* in_sizes, int n_in,
                              void* d_out, int out_size, void* d_ws, size_t ws_size,
                              hipStream_t stream) {
  const float* x      = (const float*)d_in[0];
  const int*   widx   = (const int*)d_in[1];
  const float* absmax = (const float*)d_in[2];
  const float* bias   = (const float*)d_in[3];
  float* out = (float*)d_out;

  const int N = in_sizes[3];                 // 11008
  const int K = in_sizes[1] / N;             // 4096
  const int M = in_sizes[0] / K;             // 1024
  const long long xElems = (long long)M * K;
  const size_t wsNeed = (size_t)xElems * 2;

  if (ws_size >= wsNeed && (M % BM) == 0 && (N % BN) == 0 &&
      (K % BKK) == 0 && (xElems % 2048) == 0) {
    ushort* Xbf = (ushort*)d_ws;
    f32_to_bf16<<<(int)(xElems / (256 * 8)), 256, 0, stream>>>(x, Xbf);
    const int MP = M / BM;                   // 8
    const int NB = N / BN;                   // 86
    const int grid = 8 * MP * ((NB + 7) / 8);  // padded; id->(m,n) in-kernel
    gemm_fused<<<dim3(grid), 256, 0, stream>>>(Xbf, widx, absmax, bias, out,
                                               M, N, K, MP, NB);
  } else {
    fallback_kernel<<<N, 256, 0, stream>>>(x, widx, absmax, bias, out, M, N, K);
  }
}

// Round 8
// 155.629 us; speedup vs baseline: 1.1329x; 1.1329x over previous
//
#include <hip/hip_runtime.h>
#include <hip/hip_bf16.h>
#include <stdint.h>

// ---------------------------------------------------------------------------
// NF4 dequant + linear:  out[M,N] = x[M,K] @ W[N,K]^T + bias
// R8: back to the VERIFIED two-pass structure (R1 = best measured, 153us),
// with one change: gemm_bt occupancy 2 -> 4 blocks/CU (launch_bounds 2nd arg
// is waves/EU; (256,2) had capped us at 8 waves/CU, Occupancy 22.5%).
// m114: resident-block MFMA covers the per-block barrier drain -> expect
// gemm 110 -> ~100us.  Fusion abandoned: R3-R7 all land 212-263us rocprof
// regardless of traffic/conflicts/gather-engine (structurally latency-bound).
// ---------------------------------------------------------------------------

using short8 = __attribute__((ext_vector_type(8))) short;
using f32x4  = __attribute__((ext_vector_type(4))) float;

#define AS1 __attribute__((address_space(1)))
#define AS3 __attribute__((address_space(3)))

__device__ __forceinline__ void gload16(const void* g, void* l) {
  __builtin_amdgcn_global_load_lds((const AS1 uint32_t*)g, (AS3 uint32_t*)l, 16, 0, 0);
}

__constant__ float NF4_CONST[16] = {
  -1.0f, -0.6961928009986877f, -0.5250730514526367f, -0.39491748809814453f,
  -0.28444138169288635f, -0.18477343022823334f, -0.09105003625154495f, 0.0f,
  0.07958029955625534f, 0.16093020141124725f, 0.24611230194568634f,
  0.33791524171829224f, 0.44070982933044434f, 0.5626170039176941f,
  0.7229568362236023f, 1.0f};

__device__ __forceinline__ ushort f2bf(float f) {
  union { float f; uint32_t u; } v; v.f = f;
  uint32_t r = (v.u + 0x7FFFu + ((v.u >> 16) & 1u)) >> 16;
  return (ushort)r;
}

// ---- Pass 1: dequantize w_idx(int32) * absmax -> bf16 weights -------------
__global__ __launch_bounds__(256) void dequant_nf4(
    const int* __restrict__ widx, const float* __restrict__ absmax,
    ushort* __restrict__ W) {
  __shared__ float lut[16];
  if (threadIdx.x < 16) lut[threadIdx.x] = NF4_CONST[threadIdx.x];
  __syncthreads();
  const long long t = (long long)blockIdx.x * 256 + threadIdx.x;
  const long long base = t * 8;   // 8 weights per thread, all in one 64-block
  const int4 i0 = *(const int4*)(widx + base);
  const int4 i1 = *(const int4*)(widx + base + 4);
  const float s = absmax[base >> 6];
  uint4 o;
  o.x = (uint32_t)f2bf(lut[i0.x] * s) | ((uint32_t)f2bf(lut[i0.y] * s) << 16);
  o.y = (uint32_t)f2bf(lut[i0.z] * s) | ((uint32_t)f2bf(lut[i0.w] * s) << 16);
  o.z = (uint32_t)f2bf(lut[i1.x] * s) | ((uint32_t)f2bf(lut[i1.y] * s) << 16);
  o.w = (uint32_t)f2bf(lut[i1.z] * s) | ((uint32_t)f2bf(lut[i1.w] * s) << 16);
  *(uint4*)(W + base) = o;
}

// ---- Pass 2: x f32 -> bf16 ------------------------------------------------
__global__ __launch_bounds__(256) void f32_to_bf16(
    const float* __restrict__ in, ushort* __restrict__ out) {
  const int t = blockIdx.x * 256 + threadIdx.x;
  const int base = t * 8;
  const float4 a = *(const float4*)(in + base);
  const float4 b = *(const float4*)(in + base + 4);
  uint4 o;
  o.x = (uint32_t)f2bf(a.x) | ((uint32_t)f2bf(a.y) << 16);
  o.y = (uint32_t)f2bf(a.z) | ((uint32_t)f2bf(a.w) << 16);
  o.z = (uint32_t)f2bf(b.x) | ((uint32_t)f2bf(b.y) << 16);
  o.w = (uint32_t)f2bf(b.z) | ((uint32_t)f2bf(b.w) << 16);
  *(uint4*)(out + base) = o;
}

// ---- Pass 3: bf16 GEMM, C[M,N] = A[M,K] * B[N,K]^T + bias -----------------
// 128x128 tile, BK=64, 4 waves (2x2), each wave 64x64 via 4x4 frags of
// 16x16x32.  LDS XOR-swizzle: logical slot s (16B) of row r lives at phys
// slot s^(r&7); staged via pre-swizzled global source + linear gload_lds.
// R8: min 4 waves/EU -> 4 blocks/CU resident (VGPR 60, LDS 32KB permit it).
#define BM 128
#define BN 128
#define BKK 64

__global__ __launch_bounds__(256, 4) void gemm_bt(
    const ushort* __restrict__ A, const ushort* __restrict__ B,
    const float* __restrict__ bias, float* __restrict__ C,
    const int M, const int N, const int K) {
  __shared__ char lds[(BM * BKK + BN * BKK) * 2];  // 32 KB
  const int tid  = threadIdx.x;
  const int wid  = tid >> 6;
  const int lane = tid & 63;
  const int row0 = blockIdx.y * BM;
  const int col0 = blockIdx.x * BN;
  const int wr = wid >> 1, wc = wid & 1;

  // staging source pointers (pre-swizzled global addresses)
  const ushort* gsrcA[4];
  const ushort* gsrcB[4];
#pragma unroll
  for (int i = 0; i < 4; ++i) {
    const int u = tid + i * 256;            // 16B-unit index within tile
    const int r = u >> 3;                   // tile row
    const int slog = (u & 7) ^ (r & 7);     // logical slot that lands here
    gsrcA[i] = A + (size_t)(row0 + r) * K + slog * 8;
    gsrcB[i] = B + (size_t)(col0 + r) * K + slog * 8;
  }

  // LDS read byte-offsets (loop-invariant)
  int offA[2][4], offB[2][4];
#pragma unroll
  for (int ks = 0; ks < 2; ++ks) {
#pragma unroll
    for (int m = 0; m < 4; ++m) {
      const int ra = wr * 64 + m * 16 + (lane & 15);
      offA[ks][m] = ra * 128 + (((ks * 4 + (lane >> 4)) ^ (ra & 7)) * 16);
      const int rb = wc * 64 + m * 16 + (lane & 15);
      offB[ks][m] = 16384 + rb * 128 + (((ks * 4 + (lane >> 4)) ^ (rb & 7)) * 16);
    }
  }

  f32x4 acc[4][4] = {};

  for (int kt = 0; kt < K; kt += BKK) {
#pragma unroll
    for (int i = 0; i < 4; ++i) {
      gload16(gsrcA[i] + kt, lds + i * 4096 + wid * 1024);
      gload16(gsrcB[i] + kt, lds + 16384 + i * 4096 + wid * 1024);
    }
    __syncthreads();   // compiler drains vmcnt before s_barrier
#pragma unroll
    for (int ks = 0; ks < 2; ++ks) {
      short8 af[4], bv[4];
#pragma unroll
      for (int m = 0; m < 4; ++m) af[m] = *(const short8*)(lds + offA[ks][m]);
#pragma unroll
      for (int n = 0; n < 4; ++n) bv[n] = *(const short8*)(lds + offB[ks][n]);
#pragma unroll
      for (int m = 0; m < 4; ++m)
#pragma unroll
        for (int n = 0; n < 4; ++n)
          acc[m][n] = __builtin_amdgcn_mfma_f32_16x16x32_bf16(
              af[m], bv[n], acc[m][n], 0, 0, 0);
    }
    __syncthreads();
  }

  // epilogue: C/D layout col=lane&15, row=(lane>>4)*4+j  (m89-verified)
#pragma unroll
  for (int n = 0; n < 4; ++n) {
    const int gc = col0 + wc * 64 + n * 16 + (lane & 15);
    const float bvadd = bias[gc];
#pragma unroll
    for (int m = 0; m < 4; ++m) {
      const int gr0 = row0 + wr * 64 + m * 16 + ((lane >> 4) * 4);
#pragma unroll
      for (int j = 0; j < 4; ++j)
        C[(size_t)(gr0 + j) * N + gc] = acc[m][n][j] + bvadd;
    }
  }
}

// ---- Fallback (only if ws_size too small): correct but slow ---------------
__global__ __launch_bounds__(256) void fallback_kernel(
    const float* __restrict__ x, const int* __restrict__ widx,
    const float* __restrict__ absmax, const float* __restrict__ bias,
    float* __restrict__ out, const int M, const int N, const int K) {
  __shared__ float w[4096];
  const int o = blockIdx.x;
  for (int k = threadIdx.x; k < K; k += 256) {
    const long long fi = (long long)o * K + k;
    w[k] = NF4_CONST[widx[fi]] * absmax[fi >> 6];
  }
  __syncthreads();
  for (int m = threadIdx.x; m < M; m += 256) {
    float acc = bias[o];
    const float* xr = x + (size_t)m * K;
    for (int k = 0; k < K; ++k) acc += xr[k] * w[k];
    out[(size_t)m * N + o] = acc;
  }
}

extern "C" void kernel_launch(void* const* d_in, const int* in_sizes, int n_in,
                              void* d_out, int out_size, void* d_ws, size_t ws_size,
                              hipStream_t stream) {
  const float* x      = (const float*)d_in[0];
  const int*   widx   = (const int*)d_in[1];
  const float* absmax = (const float*)d_in[2];
  const float* bias   = (const float*)d_in[3];
  float* out = (float*)d_out;

  const int N = in_sizes[3];                 // 11008
  const int K = in_sizes[1] / N;             // 4096
  const int M = in_sizes[0] / K;             // 1024
  const long long wElems = (long long)N * K; // 45,088,768
  const long long xElems = (long long)M * K; // 4,194,304
  const size_t wsNeed = (size_t)(wElems + xElems) * 2;

  if (ws_size >= wsNeed && (M % BM) == 0 && (N % BN) == 0 && (K % BKK) == 0 &&
      (wElems % 2048) == 0 && (xElems % 2048) == 0) {
    ushort* Wbf = (ushort*)d_ws;
    ushort* Xbf = (ushort*)d_ws + wElems;
    dequant_nf4<<<(int)(wElems / (256 * 8)), 256, 0, stream>>>(widx, absmax, Wbf);
    f32_to_bf16<<<(int)(xElems / (256 * 8)), 256, 0, stream>>>(x, Xbf);
    dim3 grid(N / BN, M / BM);
    gemm_bt<<<grid, 256, 0, stream>>>(Xbf, Wbf, bias, out, M, N, K);
  } else {
    fallback_kernel<<<N, 256, 0, stream>>>(x, widx, absmax, bias, out, M, N, K);
  }
}

// Round 9
// 144.704 us; speedup vs baseline: 1.2184x; 1.0755x over previous
//
#include <hip/hip_runtime.h>
#include <hip/hip_bf16.h>
#include <stdint.h>

// ---------------------------------------------------------------------------
// NF4 dequant + linear:  out[M,N] = x[M,K] @ W[N,K]^T + bias
// R9: two-pass (R1-verified kernels).  Single change: gemm_bt block->tile
// mapping uses the R5 same-XCD panel-mate map (id = nP%8 + 8*(mP + 8*q)),
// so the 8 M-blocks sharing a 1MB W N-panel are (a) on one XCD (id%8
// fixed) and (b) dispatched within a window of 8 ids -> W-panel reads are
// L2-served, shortening the per-iter vmcnt-drain latency.
// (R8 lesson: launch_bounds doesn't raise residency - grid-limited 2/CU.
//  fp8/MX paths excluded by error arithmetic: ~6%/elem -> absmax 5-7 > 2.19.)
// ---------------------------------------------------------------------------

using short8 = __attribute__((ext_vector_type(8))) short;
using f32x4  = __attribute__((ext_vector_type(4))) float;

#define AS1 __attribute__((address_space(1)))
#define AS3 __attribute__((address_space(3)))

__device__ __forceinline__ void gload16(const void* g, void* l) {
  __builtin_amdgcn_global_load_lds((const AS1 uint32_t*)g, (AS3 uint32_t*)l, 16, 0, 0);
}

__constant__ float NF4_CONST[16] = {
  -1.0f, -0.6961928009986877f, -0.5250730514526367f, -0.39491748809814453f,
  -0.28444138169288635f, -0.18477343022823334f, -0.09105003625154495f, 0.0f,
  0.07958029955625534f, 0.16093020141124725f, 0.24611230194568634f,
  0.33791524171829224f, 0.44070982933044434f, 0.5626170039176941f,
  0.7229568362236023f, 1.0f};

__device__ __forceinline__ ushort f2bf(float f) {
  union { float f; uint32_t u; } v; v.f = f;
  uint32_t r = (v.u + 0x7FFFu + ((v.u >> 16) & 1u)) >> 16;
  return (ushort)r;
}

// ---- Pass 1: dequantize w_idx(int32) * absmax -> bf16 weights -------------
__global__ __launch_bounds__(256) void dequant_nf4(
    const int* __restrict__ widx, const float* __restrict__ absmax,
    ushort* __restrict__ W) {
  __shared__ float lut[16];
  if (threadIdx.x < 16) lut[threadIdx.x] = NF4_CONST[threadIdx.x];
  __syncthreads();
  const long long t = (long long)blockIdx.x * 256 + threadIdx.x;
  const long long base = t * 8;   // 8 weights per thread, all in one 64-block
  const int4 i0 = *(const int4*)(widx + base);
  const int4 i1 = *(const int4*)(widx + base + 4);
  const float s = absmax[base >> 6];
  uint4 o;
  o.x = (uint32_t)f2bf(lut[i0.x] * s) | ((uint32_t)f2bf(lut[i0.y] * s) << 16);
  o.y = (uint32_t)f2bf(lut[i0.z] * s) | ((uint32_t)f2bf(lut[i0.w] * s) << 16);
  o.z = (uint32_t)f2bf(lut[i1.x] * s) | ((uint32_t)f2bf(lut[i1.y] * s) << 16);
  o.w = (uint32_t)f2bf(lut[i1.z] * s) | ((uint32_t)f2bf(lut[i1.w] * s) << 16);
  *(uint4*)(W + base) = o;
}

// ---- Pass 2: x f32 -> bf16 ------------------------------------------------
__global__ __launch_bounds__(256) void f32_to_bf16(
    const float* __restrict__ in, ushort* __restrict__ out) {
  const int t = blockIdx.x * 256 + threadIdx.x;
  const int base = t * 8;
  const float4 a = *(const float4*)(in + base);
  const float4 b = *(const float4*)(in + base + 4);
  uint4 o;
  o.x = (uint32_t)f2bf(a.x) | ((uint32_t)f2bf(a.y) << 16);
  o.y = (uint32_t)f2bf(a.z) | ((uint32_t)f2bf(a.w) << 16);
  o.z = (uint32_t)f2bf(b.x) | ((uint32_t)f2bf(b.y) << 16);
  o.w = (uint32_t)f2bf(b.z) | ((uint32_t)f2bf(b.w) << 16);
  *(uint4*)(out + base) = o;
}

// ---- Pass 3: bf16 GEMM, C[M,N] = A[M,K] * B[N,K]^T + bias -----------------
// 128x128 tile, BK=64, 4 waves (2x2), each wave 64x64 via 4x4 frags of
// 16x16x32.  LDS XOR-swizzle: logical slot s (16B) of row r lives at phys
// slot s^(r&7); staged via pre-swizzled global source + linear gload_lds.
// R9: 1-D grid with same-XCD panel-mate map (see header comment).
#define BM 128
#define BN 128
#define BKK 64

__global__ __launch_bounds__(256, 2) void gemm_bt(
    const ushort* __restrict__ A, const ushort* __restrict__ B,
    const float* __restrict__ bias, float* __restrict__ C,
    const int M, const int N, const int K, const int MP, const int NB) {
  __shared__ char lds[(BM * BKK + BN * BKK) * 2];  // 32 KB
  const int tid  = threadIdx.x;
  const int wid  = tid >> 6;
  const int lane = tid & 63;

  // same-XCD panel-mate map: id = r8 + 8*(mP + MP*q), nP = 8q + r8.
  // -> a W N-panel's MP mates share id%8 (one XCD) and sit in one id-window.
  const int r8 = blockIdx.x & 7;
  const int w  = blockIdx.x >> 3;
  const int mP = w % MP;
  const int q  = w / MP;
  const int nP = (q << 3) + r8;
  if (nP >= NB) return;                 // uniform early exit (padded grid)
  const int row0 = mP * BM;
  const int col0 = nP * BN;
  const int wr = wid >> 1, wc = wid & 1;

  // staging source pointers (pre-swizzled global addresses)
  const ushort* gsrcA[4];
  const ushort* gsrcB[4];
#pragma unroll
  for (int i = 0; i < 4; ++i) {
    const int u = tid + i * 256;            // 16B-unit index within tile
    const int r = u >> 3;                   // tile row
    const int slog = (u & 7) ^ (r & 7);     // logical slot that lands here
    gsrcA[i] = A + (size_t)(row0 + r) * K + slog * 8;
    gsrcB[i] = B + (size_t)(col0 + r) * K + slog * 8;
  }

  // LDS read byte-offsets (loop-invariant)
  int offA[2][4], offB[2][4];
#pragma unroll
  for (int ks = 0; ks < 2; ++ks) {
#pragma unroll
    for (int m = 0; m < 4; ++m) {
      const int ra = wr * 64 + m * 16 + (lane & 15);
      offA[ks][m] = ra * 128 + (((ks * 4 + (lane >> 4)) ^ (ra & 7)) * 16);
      const int rb = wc * 64 + m * 16 + (lane & 15);
      offB[ks][m] = 16384 + rb * 128 + (((ks * 4 + (lane >> 4)) ^ (rb & 7)) * 16);
    }
  }

  f32x4 acc[4][4] = {};

  for (int kt = 0; kt < K; kt += BKK) {
#pragma unroll
    for (int i = 0; i < 4; ++i) {
      gload16(gsrcA[i] + kt, lds + i * 4096 + wid * 1024);
      gload16(gsrcB[i] + kt, lds + 16384 + i * 4096 + wid * 1024);
    }
    __syncthreads();   // compiler drains vmcnt before s_barrier
#pragma unroll
    for (int ks = 0; ks < 2; ++ks) {
      short8 af[4], bv[4];
#pragma unroll
      for (int m = 0; m < 4; ++m) af[m] = *(const short8*)(lds + offA[ks][m]);
#pragma unroll
      for (int n = 0; n < 4; ++n) bv[n] = *(const short8*)(lds + offB[ks][n]);
#pragma unroll
      for (int m = 0; m < 4; ++m)
#pragma unroll
        for (int n = 0; n < 4; ++n)
          acc[m][n] = __builtin_amdgcn_mfma_f32_16x16x32_bf16(
              af[m], bv[n], acc[m][n], 0, 0, 0);
    }
    __syncthreads();
  }

  // epilogue: C/D layout col=lane&15, row=(lane>>4)*4+j  (m89-verified)
#pragma unroll
  for (int n = 0; n < 4; ++n) {
    const int gc = col0 + wc * 64 + n * 16 + (lane & 15);
    const float bvadd = bias[gc];
#pragma unroll
    for (int m = 0; m < 4; ++m) {
      const int gr0 = row0 + wr * 64 + m * 16 + ((lane >> 4) * 4);
#pragma unroll
      for (int j = 0; j < 4; ++j)
        C[(size_t)(gr0 + j) * N + gc] = acc[m][n][j] + bvadd;
    }
  }
}

// ---- Fallback (only if ws_size too small): correct but slow ---------------
__global__ __launch_bounds__(256) void fallback_kernel(
    const float* __restrict__ x, const int* __restrict__ widx,
    const float* __restrict__ absmax, const float* __restrict__ bias,
    float* __restrict__ out, const int M, const int N, const int K) {
  __shared__ float w[4096];
  const int o = blockIdx.x;
  for (int k = threadIdx.x; k < K; k += 256) {
    const long long fi = (long long)o * K + k;
    w[k] = NF4_CONST[widx[fi]] * absmax[fi >> 6];
  }
  __syncthreads();
  for (int m = threadIdx.x; m < M; m += 256) {
    float acc = bias[o];
    const float* xr = x + (size_t)m * K;
    for (int k = 0; k < K; ++k) acc += xr[k] * w[k];
    out[(size_t)m * N + o] = acc;
  }
}

extern "C" void kernel_launch(void* const* d_in, const int* in_sizes, int n_in,
                              void* d_out, int out_size, void* d_ws, size_t ws_size,
                              hipStream_t stream) {
  const float* x      = (const float*)d_in[0];
  const int*   widx   = (const int*)d_in[1];
  const float* absmax = (const float*)d_in[2];
  const float* bias   = (const float*)d_in[3];
  float* out = (float*)d_out;

  const int N = in_sizes[3];                 // 11008
  const int K = in_sizes[1] / N;             // 4096
  const int M = in_sizes[0] / K;             // 1024
  const long long wElems = (long long)N * K; // 45,088,768
  const long long xElems = (long long)M * K; // 4,194,304
  const size_t wsNeed = (size_t)(wElems + xElems) * 2;

  if (ws_size >= wsNeed && (M % BM) == 0 && (N % BN) == 0 && (K % BKK) == 0 &&
      (wElems % 2048) == 0 && (xElems % 2048) == 0) {
    ushort* Wbf = (ushort*)d_ws;
    ushort* Xbf = (ushort*)d_ws + wElems;
    dequant_nf4<<<(int)(wElems / (256 * 8)), 256, 0, stream>>>(widx, absmax, Wbf);
    f32_to_bf16<<<(int)(xElems / (256 * 8)), 256, 0, stream>>>(x, Xbf);
    const int MP = M / BM;                    // 8
    const int NB = N / BN;                    // 86
    const int grid = 8 * MP * ((NB + 7) / 8); // 704 (16 padded no-ops)
    gemm_bt<<<dim3(grid), 256, 0, stream>>>(Xbf, Wbf, bias, out, M, N, K, MP, NB);
  } else {
    fallback_kernel<<<N, 256, 0, stream>>>(x, widx, absmax, bias, out, M, N, K);
  }
}